// Round 5
// baseline (727.745 us; speedup 1.0000x reference)
//
#include <hip/hip_runtime.h>
#include <hip/hip_bf16.h>

// Problem constants
#define B_SZ 8192
#define D_SZ 512
#define K_SZ 4096
#define L_SZ 16
#define M_ALL (B_SZ + K_SZ)   // 12288 rows: targets stacked over codebook

typedef __attribute__((ext_vector_type(8))) short short8v;      // 8 bf16
typedef __attribute__((ext_vector_type(4))) float f32x4;
typedef _Float16 half8v __attribute__((ext_vector_type(8)));    // 8 fp16 = 16B
typedef _Float16 h2 __attribute__((ext_vector_type(2)));        // packed fp16 pair
struct H2x4 { h2 a, b, c, d; };                                 // = one half8v

static __device__ __forceinline__ h2 habs2(h2 a) {
    unsigned u = __builtin_bit_cast(unsigned, a) & 0x7FFF7FFFu;
    return __builtin_bit_cast(h2, u);
}
static __device__ __forceinline__ h2 hmax2(h2 a, h2 b) {
#if __has_builtin(__builtin_elementwise_max)
    return __builtin_elementwise_max(a, b);
#else
    h2 r; r[0] = a[0] > b[0] ? a[0] : b[0]; r[1] = a[1] > b[1] ? a[1] : b[1]; return r;
#endif
}

// ---------------------------------------------------------------------------
// Kernel 1: cast targets+codebook (fp32) into one stacked bf16 matrix [12288 x 512]
// ---------------------------------------------------------------------------
__global__ void cast_bf16_kernel(const float* __restrict__ targets,
                                 const float* __restrict__ codebook,
                                 __hip_bfloat16* __restrict__ abf) {
    int idx = blockIdx.x * blockDim.x + threadIdx.x;
    const int total4 = (M_ALL * D_SZ) / 4;
    if (idx >= total4) return;
    int base = idx * 4;
    const float* src = (base < B_SZ * D_SZ) ? (targets + base)
                                            : (codebook + (base - B_SZ * D_SZ));
    float4 v = *(const float4*)src;
    abf[base + 0] = __float2bfloat16(v.x);
    abf[base + 1] = __float2bfloat16(v.y);
    abf[base + 2] = __float2bfloat16(v.z);
    abf[base + 3] = __float2bfloat16(v.w);
}

// ---------------------------------------------------------------------------
// Kernel 1b: exact fp64 codebook row norms^2 (for algebraic ||r||^2 update)
// ---------------------------------------------------------------------------
__global__ void cn2_kernel(const float* __restrict__ codebook,
                           double* __restrict__ cn2) {
    int row  = blockIdx.x * 4 + (threadIdx.x >> 6);
    int lane = threadIdx.x & 63;
    const float* r = codebook + (size_t)row * D_SZ;
    double s = 0.0;
#pragma unroll
    for (int j = 0; j < 8; j++) { double v = (double)r[lane + 64 * j]; s += v * v; }
#pragma unroll
    for (int o = 32; o > 0; o >>= 1) s += __shfl_down(s, o, 64);
    if (lane == 0) cn2[row] = s;
}

// ---------------------------------------------------------------------------
// Kernel 2: S = A * B^T -> fp16 [M x 4096]. 128x128 tile, 4 waves, 16x16x32 MFMA.
// ---------------------------------------------------------------------------
#define BM 128
#define BN 128
#define BK 32
#define LDSS 40

__global__ __launch_bounds__(256, 2)
void gemm_bt_kernel(const __hip_bfloat16* __restrict__ A,
                    const __hip_bfloat16* __restrict__ Bm,
                    _Float16* __restrict__ C) {
    __shared__ short As[BM * LDSS];
    __shared__ short Bs[BN * LDSS];
    const int tid  = threadIdx.x;
    const int bm   = blockIdx.y * BM;
    const int bn   = blockIdx.x * BN;
    const int wave = tid >> 6, lane = tid & 63;
    const int wm = (wave & 1) * 64, wn = (wave >> 1) * 64;
    const int row16 = lane & 15, quad = lane >> 4;
    const int koff = quad * 8;

    f32x4 acc[4][4] = {};

    const int srow = tid >> 1;
    const int scol = (tid & 1) * 16;
    const short* Ag = (const short*)A;
    const short* Bg = (const short*)Bm;

    for (int k0 = 0; k0 < D_SZ; k0 += BK) {
        short8v a0 = *(const short8v*)(Ag + (size_t)(bm + srow) * D_SZ + k0 + scol);
        short8v a1 = *(const short8v*)(Ag + (size_t)(bm + srow) * D_SZ + k0 + scol + 8);
        short8v b0 = *(const short8v*)(Bg + (size_t)(bn + srow) * D_SZ + k0 + scol);
        short8v b1 = *(const short8v*)(Bg + (size_t)(bn + srow) * D_SZ + k0 + scol + 8);
        __syncthreads();
        *(short8v*)(As + srow * LDSS + scol)     = a0;
        *(short8v*)(As + srow * LDSS + scol + 8) = a1;
        *(short8v*)(Bs + srow * LDSS + scol)     = b0;
        *(short8v*)(Bs + srow * LDSS + scol + 8) = b1;
        __syncthreads();

        short8v af[4], bf[4];
#pragma unroll
        for (int i = 0; i < 4; i++)
            af[i] = *(const short8v*)(As + (wm + i * 16 + row16) * LDSS + koff);
#pragma unroll
        for (int j = 0; j < 4; j++)
            bf[j] = *(const short8v*)(Bs + (wn + j * 16 + row16) * LDSS + koff);
#pragma unroll
        for (int i = 0; i < 4; i++)
#pragma unroll
            for (int j = 0; j < 4; j++)
                acc[i][j] = __builtin_amdgcn_mfma_f32_16x16x32_bf16(af[i], bf[j], acc[i][j], 0, 0, 0);
    }

#pragma unroll
    for (int i = 0; i < 4; i++) {
        int grow = bm + wm + i * 16 + quad * 4;
#pragma unroll
        for (int j = 0; j < 4; j++) {
            int gcol = bn + wn + j * 16 + row16;
#pragma unroll
            for (int r = 0; r < 4; r++)
                C[(size_t)(grow + r) * K_SZ + gcol] = (_Float16)acc[i][j][r];
        }
    }
}

// ---------------------------------------------------------------------------
// Kernel 3: pursuit, wave-per-row. VGPR budget engineered for <=64 so 8
// waves/SIMD fit (m69: waves/CU halves at 64): g packed fp16 in 32 regs
// (lane owns k = jb*512 + lane*8 + e), fp64 residual in LDS (transposed:
// [e*64+lane], 4-way bank aliasing only). Diagonal Gram error patched
// exactly in fp64. nc==1 fast path: Gram row loads concurrently with
// codebook row (one latency round per step).
// ---------------------------------------------------------------------------
#define MAXC 16
#define MARGIN 1.25f

__global__ __launch_bounds__(256, 8)
void pursuit_kernel(const float* __restrict__ targets,
                    const float* __restrict__ codebook,
                    const _Float16* __restrict__ S,   // [12288 x 4096]; rows >=8192 are Gram
                    const double* __restrict__ cn2,   // [4096] exact ||c_k||^2
                    float* __restrict__ out) {
    const int wave = threadIdx.x >> 6;
    const int lane = threadIdx.x & 63;
    const int b = blockIdx.x * 4 + wave;
    const int lane8 = lane * 8;

    __shared__ double rres_s[4][D_SZ];
    __shared__ int s_cnt[4];
    __shared__ int s_cand[4][MAXC];
    double* rres = rres_s[wave];
    int* cnt  = &s_cnt[wave];
    int* cand = s_cand[wave];

#define RL(e) rres[(e) * 64 + lane]

    // ---- g regs (packed fp16) straight from fp16 score row: no converts ----
    h2 g2[32];
    {
        const _Float16* g0 = S + (size_t)b * K_SZ + lane8;
#pragma unroll
        for (int jb = 0; jb < 8; jb++) {
            H2x4 u = __builtin_bit_cast(H2x4, *(const half8v*)(g0 + jb * 512));
            g2[jb * 4 + 0] = u.a; g2[jb * 4 + 1] = u.b;
            g2[jb * 4 + 2] = u.c; g2[jb * 4 + 3] = u.d;
        }
    }

    // ---- residual -> LDS (transposed), tn2 via butterfly ----
    double loc = 0.0;
    {
        const float* tg = targets + (size_t)b * D_SZ + lane8;
        float4 t0 = *(const float4*)tg;
        float4 t1 = *(const float4*)(tg + 4);
        RL(0) = t0.x; RL(1) = t0.y; RL(2) = t0.z; RL(3) = t0.w;
        RL(4) = t1.x; RL(5) = t1.y; RL(6) = t1.z; RL(7) = t1.w;
        loc = (double)t0.x * t0.x + (double)t0.y * t0.y + (double)t0.z * t0.z
            + (double)t0.w * t0.w + (double)t1.x * t1.x + (double)t1.y * t1.y
            + (double)t1.z * t1.z + (double)t1.w * t1.w;
    }
#pragma unroll
    for (int o = 32; o > 0; o >>= 1) loc += __shfl_xor(loc, o, 64);
    double rn2 = loc;
    const bool tgt_ok = (sqrt(loc) >= 1e-8);

    float* out_seq  = out + (size_t)b * L_SZ;
    float* out_mask = out + (size_t)B_SZ * L_SZ + (size_t)b * L_SZ;
    float* out_res  = out + (size_t)2 * B_SZ * L_SZ + (size_t)b * D_SZ;

    // lane-local packed max tree (31 pk-max ops, depth 5)
    auto lanemax = [&]() -> float {
        h2 t[16];
#pragma unroll
        for (int j = 0; j < 16; j++) t[j] = hmax2(habs2(g2[j]), habs2(g2[j + 16]));
#pragma unroll
        for (int j = 0; j < 8; j++)  t[j] = hmax2(t[j], t[j + 8]);
#pragma unroll
        for (int j = 0; j < 4; j++)  t[j] = hmax2(t[j], t[j + 4]);
        h2 f = hmax2(hmax2(t[0], t[1]), hmax2(t[2], t[3]));
        return fmaxf((float)f[0], (float)f[1]);
    };

    float m = lanemax();
    double decay = 1.0;

    for (int t = 0; t < L_SZ; t++) {
        decay *= 0.95;
        bool active = (sqrt(rn2) >= 0.01) && tgt_ok;   // wave-uniform
        if (!active) {                                 // stays inactive forever
            if (lane == 0)
                for (int tt = t; tt < L_SZ; tt++) { out_seq[tt] = 0.0f; out_mask[tt] = 0.0f; }
            break;
        }

        // ---- wave max + threshold ----
        float M = m;
#pragma unroll
        for (int o = 32; o > 0; o >>= 1) M = fmaxf(M, __shfl_xor(M, o, 64));
        float thr = M - MARGIN;

        // ---- candidate collection (guarded: usually 1-2 lanes scan) ----
        if (lane == 0) *cnt = 0;
        if (m >= thr) {
#pragma unroll
            for (int p = 0; p < 32; p++) {
                float f0 = (float)g2[p][0], f1 = (float)g2[p][1];
                int kbase = (p >> 2) * 512 + lane8 + ((p & 3) * 2);
                if (fabsf(f0) >= thr) { int q = atomicAdd(cnt, 1); if (q < MAXC) cand[q] = kbase; }
                if (fabsf(f1) >= thr) { int q = atomicAdd(cnt, 1); if (q < MAXC) cand[q] = kbase + 1; }
            }
        }
        __threadfence_block();
        int nc = min(*cnt, MAXC);

        int bk; double bv;
        float4 c0, c1;
        half8v Ga, Gb;
        const _Float16* Gp;

        if (nc == 1) {
            // ---- fast path: single candidate IS the winner; Gram row loads
            //      concurrently with codebook row (one latency round) ----
            bk = __builtin_amdgcn_readfirstlane(cand[0]);
            const float* cr = codebook + (size_t)bk * D_SZ + lane8;
            Gp = S + (size_t)(B_SZ + bk) * K_SZ + lane8;
            c0 = *(const float4*)cr;
            c1 = *(const float4*)(cr + 4);
            Ga = *(const half8v*)(Gp);
            Gb = *(const half8v*)(Gp + 512);
            double s = RL(0) * (double)c0.x + RL(1) * (double)c0.y
                     + RL(2) * (double)c0.z + RL(3) * (double)c0.w
                     + RL(4) * (double)c1.x + RL(5) * (double)c1.y
                     + RL(6) * (double)c1.z + RL(7) * (double)c1.w;
#pragma unroll
            for (int o = 32; o > 0; o >>= 1) s += __shfl_xor(s, o, 64);
            bv = s;
        } else {
            // ---- slow path (~16%): exact rescore of every candidate ----
            bk = -1; bv = 0.0;
            for (int ci = 0; ci < nc; ci++) {
                int k = __builtin_amdgcn_readfirstlane(cand[ci]);
                const float* cr = codebook + (size_t)k * D_SZ + lane8;
                float4 d0 = *(const float4*)cr;
                float4 d1 = *(const float4*)(cr + 4);
                double s = RL(0) * (double)d0.x + RL(1) * (double)d0.y
                         + RL(2) * (double)d0.z + RL(3) * (double)d0.w
                         + RL(4) * (double)d1.x + RL(5) * (double)d1.y
                         + RL(6) * (double)d1.z + RL(7) * (double)d1.w;
#pragma unroll
                for (int o = 32; o > 0; o >>= 1) s += __shfl_xor(s, o, 64);
                if (bk < 0 || fabs(s) > fabs(bv) ||
                    (fabs(s) == fabs(bv) && k < bk)) { bk = k; bv = s; }
            }
            // winner codebook + Gram reload (one combined round)
            const float* cr = codebook + (size_t)bk * D_SZ + lane8;
            Gp = S + (size_t)(B_SZ + bk) * K_SZ + lane8;
            c0 = *(const float4*)cr;
            c1 = *(const float4*)(cr + 4);
            Ga = *(const half8v*)(Gp);
            Gb = *(const half8v*)(Gp + 512);
        }

        // ---- decision + exact ||r||^2 identity + outputs ----
        const double cn2bk = cn2[bk];
        double sd = ((bv >= 0.0) ? 1.0 : -1.0) * decay;
        rn2 = rn2 - 2.0 * sd * bv + sd * sd * cn2bk;
        if (lane == 0) {
            out_seq[t]  = (float)((bv >= 0.0) ? bk : (-bk - 1));
            out_mask[t] = 1.0f;
        }
        const float sdf = (float)sd;
        h2 sdh2; sdh2[0] = (_Float16)sdf; sdh2[1] = (_Float16)sdf;

        // ---- packed g update, Gram row staged 2 chunks at a time ----
#pragma unroll
        for (int jb = 0; jb < 8; jb += 2) {
            half8v Gc, Gd;
            if (jb + 2 < 8) {
                Gc = *(const half8v*)(Gp + (jb + 2) * 512);
                Gd = *(const half8v*)(Gp + (jb + 3) * 512);
            }
            H2x4 ua = __builtin_bit_cast(H2x4, Ga);
            H2x4 ub = __builtin_bit_cast(H2x4, Gb);
            g2[jb * 4 + 0] -= sdh2 * ua.a; g2[jb * 4 + 1] -= sdh2 * ua.b;
            g2[jb * 4 + 2] -= sdh2 * ua.c; g2[jb * 4 + 3] -= sdh2 * ua.d;
            g2[jb * 4 + 4] -= sdh2 * ub.a; g2[jb * 4 + 5] -= sdh2 * ub.b;
            g2[jb * 4 + 6] -= sdh2 * ub.c; g2[jb * 4 + 7] -= sdh2 * ub.d;
            Ga = Gc; Gb = Gd;
        }

        // ---- exact diagonal patch: g[bk] := fp16(bv - sd*||c_bk||^2) ----
        {
            float pf = (float)(bv - sd * cn2bk);
            int rloc = bk & 511;
            int lown = rloc >> 3;
            int eo   = rloc & 7;
            int pown = (bk >> 9) * 4 + (eo >> 1);
#pragma unroll
            for (int p = 0; p < 32; p++)
                if (p == pown) {                      // uniform branch
                    if (lane == lown) {
                        h2 v = g2[p];
                        if ((eo & 1) == 0) v[0] = (_Float16)pf; else v[1] = (_Float16)pf;
                        g2[p] = v;
                    }
                }
        }

        // ---- exact fp64 residual update (winner row in regs) ----
        RL(0) -= sd * (double)c0.x; RL(1) -= sd * (double)c0.y;
        RL(2) -= sd * (double)c0.z; RL(3) -= sd * (double)c0.w;
        RL(4) -= sd * (double)c1.x; RL(5) -= sd * (double)c1.y;
        RL(6) -= sd * (double)c1.z; RL(7) -= sd * (double)c1.w;

        // ---- lane max for next step (after patch) ----
        m = lanemax();
    }

    // ---- final residual ----
    {
        float4 r0, r1;
        r0.x = (float)RL(0); r0.y = (float)RL(1); r0.z = (float)RL(2); r0.w = (float)RL(3);
        r1.x = (float)RL(4); r1.y = (float)RL(5); r1.z = (float)RL(6); r1.w = (float)RL(7);
        *(float4*)(out_res + lane8) = r0;
        *(float4*)(out_res + lane8 + 4) = r1;
    }
#undef RL
}

// ---------------------------------------------------------------------------
extern "C" void kernel_launch(void* const* d_in, const int* in_sizes, int n_in,
                              void* d_out, int out_size, void* d_ws, size_t ws_size,
                              hipStream_t stream) {
    const float* targets  = (const float*)d_in[0];
    const float* codebook = (const float*)d_in[1];
    float* out = (float*)d_out;

    __hip_bfloat16* abf = (__hip_bfloat16*)d_ws;                         // 12,582,912 B
    _Float16* S = (_Float16*)((char*)d_ws + (size_t)M_ALL * D_SZ * 2);   // 100,663,296 B
    double* cn2 = (double*)((char*)d_ws + (size_t)M_ALL * D_SZ * 2
                                        + (size_t)M_ALL * K_SZ * 2);     // 32,768 B
    // total ws needed: ~113.3 MB

    int total4 = (M_ALL * D_SZ) / 4;
    cast_bf16_kernel<<<(total4 + 255) / 256, 256, 0, stream>>>(targets, codebook, abf);
    cn2_kernel<<<K_SZ / 4, 256, 0, stream>>>(codebook, cn2);

    dim3 ggrid(K_SZ / BN, M_ALL / BM);
    gemm_bt_kernel<<<ggrid, 256, 0, stream>>>(abf, abf + (size_t)B_SZ * D_SZ, S);

    pursuit_kernel<<<B_SZ / 4, 256, 0, stream>>>(targets, codebook, S, cn2, out);
}

// Round 6
// 343.087 us; speedup vs baseline: 2.1212x; 2.1212x over previous
//
#include <hip/hip_runtime.h>
#include <hip/hip_bf16.h>

// Problem constants
#define B_SZ 8192
#define D_SZ 512
#define K_SZ 4096
#define L_SZ 16
#define M_ALL (B_SZ + K_SZ)   // 12288 rows: targets stacked over codebook

typedef __attribute__((ext_vector_type(8))) short short8v;      // 8 bf16
typedef __attribute__((ext_vector_type(4))) float f32x4;
typedef _Float16 half8v __attribute__((ext_vector_type(8)));    // 8 fp16 = 16B
typedef _Float16 h2 __attribute__((ext_vector_type(2)));        // packed fp16 pair
struct H2x4 { h2 a, b, c, d; };                                 // = one half8v

static __device__ __forceinline__ h2 habs2(h2 a) {
    unsigned u = __builtin_bit_cast(unsigned, a) & 0x7FFF7FFFu;
    return __builtin_bit_cast(h2, u);
}
static __device__ __forceinline__ h2 hmax2(h2 a, h2 b) {
#if __has_builtin(__builtin_elementwise_max)
    return __builtin_elementwise_max(a, b);
#else
    h2 r; r[0] = a[0] > b[0] ? a[0] : b[0]; r[1] = a[1] > b[1] ? a[1] : b[1]; return r;
#endif
}

// ---------------------------------------------------------------------------
// Kernel 1: cast targets+codebook (fp32) into one stacked bf16 matrix [12288 x 512]
// ---------------------------------------------------------------------------
__global__ void cast_bf16_kernel(const float* __restrict__ targets,
                                 const float* __restrict__ codebook,
                                 __hip_bfloat16* __restrict__ abf) {
    int idx = blockIdx.x * blockDim.x + threadIdx.x;
    const int total4 = (M_ALL * D_SZ) / 4;
    if (idx >= total4) return;
    int base = idx * 4;
    const float* src = (base < B_SZ * D_SZ) ? (targets + base)
                                            : (codebook + (base - B_SZ * D_SZ));
    float4 v = *(const float4*)src;
    abf[base + 0] = __float2bfloat16(v.x);
    abf[base + 1] = __float2bfloat16(v.y);
    abf[base + 2] = __float2bfloat16(v.z);
    abf[base + 3] = __float2bfloat16(v.w);
}

// ---------------------------------------------------------------------------
// Kernel 1b: exact fp64 codebook row norms^2 (for algebraic ||r||^2 update)
// ---------------------------------------------------------------------------
__global__ void cn2_kernel(const float* __restrict__ codebook,
                           double* __restrict__ cn2) {
    int row  = blockIdx.x * 4 + (threadIdx.x >> 6);
    int lane = threadIdx.x & 63;
    const float* r = codebook + (size_t)row * D_SZ;
    double s = 0.0;
#pragma unroll
    for (int j = 0; j < 8; j++) { double v = (double)r[lane + 64 * j]; s += v * v; }
#pragma unroll
    for (int o = 32; o > 0; o >>= 1) s += __shfl_down(s, o, 64);
    if (lane == 0) cn2[row] = s;
}

// ---------------------------------------------------------------------------
// Kernel 2: S = A * B^T -> fp16 [M x 4096]. 128x128 tile, 4 waves, 16x16x32 MFMA.
// ---------------------------------------------------------------------------
#define BM 128
#define BN 128
#define BK 32
#define LDSS 40

__global__ __launch_bounds__(256, 2)
void gemm_bt_kernel(const __hip_bfloat16* __restrict__ A,
                    const __hip_bfloat16* __restrict__ Bm,
                    _Float16* __restrict__ C) {
    __shared__ short As[BM * LDSS];
    __shared__ short Bs[BN * LDSS];
    const int tid  = threadIdx.x;
    const int bm   = blockIdx.y * BM;
    const int bn   = blockIdx.x * BN;
    const int wave = tid >> 6, lane = tid & 63;
    const int wm = (wave & 1) * 64, wn = (wave >> 1) * 64;
    const int row16 = lane & 15, quad = lane >> 4;
    const int koff = quad * 8;

    f32x4 acc[4][4] = {};

    const int srow = tid >> 1;
    const int scol = (tid & 1) * 16;
    const short* Ag = (const short*)A;
    const short* Bg = (const short*)Bm;

    for (int k0 = 0; k0 < D_SZ; k0 += BK) {
        short8v a0 = *(const short8v*)(Ag + (size_t)(bm + srow) * D_SZ + k0 + scol);
        short8v a1 = *(const short8v*)(Ag + (size_t)(bm + srow) * D_SZ + k0 + scol + 8);
        short8v b0 = *(const short8v*)(Bg + (size_t)(bn + srow) * D_SZ + k0 + scol);
        short8v b1 = *(const short8v*)(Bg + (size_t)(bn + srow) * D_SZ + k0 + scol + 8);
        __syncthreads();
        *(short8v*)(As + srow * LDSS + scol)     = a0;
        *(short8v*)(As + srow * LDSS + scol + 8) = a1;
        *(short8v*)(Bs + srow * LDSS + scol)     = b0;
        *(short8v*)(Bs + srow * LDSS + scol + 8) = b1;
        __syncthreads();

        short8v af[4], bf[4];
#pragma unroll
        for (int i = 0; i < 4; i++)
            af[i] = *(const short8v*)(As + (wm + i * 16 + row16) * LDSS + koff);
#pragma unroll
        for (int j = 0; j < 4; j++)
            bf[j] = *(const short8v*)(Bs + (wn + j * 16 + row16) * LDSS + koff);
#pragma unroll
        for (int i = 0; i < 4; i++)
#pragma unroll
            for (int j = 0; j < 4; j++)
                acc[i][j] = __builtin_amdgcn_mfma_f32_16x16x32_bf16(af[i], bf[j], acc[i][j], 0, 0, 0);
    }

#pragma unroll
    for (int i = 0; i < 4; i++) {
        int grow = bm + wm + i * 16 + quad * 4;
#pragma unroll
        for (int j = 0; j < 4; j++) {
            int gcol = bn + wn + j * 16 + row16;
#pragma unroll
            for (int r = 0; r < 4; r++)
                C[(size_t)(grow + r) * K_SZ + gcol] = (_Float16)acc[i][j][r];
        }
    }
}

// ---------------------------------------------------------------------------
// Kernel 3: pursuit, wave-per-row, g in LDS as fp16 (8 KB/row, linear layout,
// conflict-free b128 pattern: lane L handles 16B granules at c*1024 + L*16).
// Persistent regs: rres[8] fp64 (lane-private: i = lane*8+e) + m + rn2 only
// (~24 VGPRs -> NO spill; R3/R5 lesson: big persistent reg arrays get
// spilled). Fused Gram-RMW + next-step max scan. Exact fp64 rescore of
// margin candidates; exact diagonal patch; algebraic ||r||^2.
// ---------------------------------------------------------------------------
#define MAXC 16
#define MARGIN 1.5f

__global__ __launch_bounds__(256, 4)
void pursuit_kernel(const float* __restrict__ targets,
                    const float* __restrict__ codebook,
                    const _Float16* __restrict__ S,   // [12288 x 4096]; rows >=8192 are Gram
                    const double* __restrict__ cn2,   // [4096] exact ||c_k||^2
                    float* __restrict__ out) {
    const int wave = threadIdx.x >> 6;
    const int lane = threadIdx.x & 63;
    const int b = blockIdx.x * 4 + wave;
    const int lane8 = lane * 8;

    __shared__ alignas(16) _Float16 g_s[4][K_SZ];
    __shared__ int s_cnt[4];
    __shared__ int s_cand[4][MAXC];
    _Float16* g = g_s[wave];
    int* cnt  = &s_cnt[wave];
    int* cand = s_cand[wave];

    // ---- init: score row -> LDS, lane max computed in flight ----
    h2 tmax; tmax[0] = (_Float16)0; tmax[1] = (_Float16)0;
    {
        const _Float16* g0 = S + (size_t)b * K_SZ + lane8;
#pragma unroll
        for (int c = 0; c < 8; c++) {
            half8v h = *(const half8v*)(g0 + c * 512);
            *(half8v*)&g[c * 512 + lane8] = h;
            H2x4 u = __builtin_bit_cast(H2x4, h);
            tmax = hmax2(tmax, hmax2(hmax2(habs2(u.a), habs2(u.b)),
                                     hmax2(habs2(u.c), habs2(u.d))));
        }
    }
    float m = fmaxf((float)tmax[0], (float)tmax[1]);

    // ---- lane-private fp64 residual + tn2 ----
    double rres[8];
    double loc = 0.0;
    {
        const float* tg = targets + (size_t)b * D_SZ + lane8;
        float4 t0 = *(const float4*)tg;
        float4 t1 = *(const float4*)(tg + 4);
        rres[0] = t0.x; rres[1] = t0.y; rres[2] = t0.z; rres[3] = t0.w;
        rres[4] = t1.x; rres[5] = t1.y; rres[6] = t1.z; rres[7] = t1.w;
#pragma unroll
        for (int e = 0; e < 8; e++) loc += rres[e] * rres[e];
    }
#pragma unroll
    for (int o = 32; o > 0; o >>= 1) loc += __shfl_xor(loc, o, 64);
    double rn2 = loc;
    const bool tgt_ok = (sqrt(loc) >= 1e-8);

    float* out_seq  = out + (size_t)b * L_SZ;
    float* out_mask = out + (size_t)B_SZ * L_SZ + (size_t)b * L_SZ;
    float* out_res  = out + (size_t)2 * B_SZ * L_SZ + (size_t)b * D_SZ;

    double decay = 1.0;

    for (int t = 0; t < L_SZ; t++) {
        decay *= 0.95;
        bool active = (sqrt(rn2) >= 0.01) && tgt_ok;   // wave-uniform
        if (!active) {                                 // stays inactive forever
            if (lane == 0)
                for (int tt = t; tt < L_SZ; tt++) { out_seq[tt] = 0.0f; out_mask[tt] = 0.0f; }
            break;
        }

        // ---- wave max + threshold ----
        float M = m;
#pragma unroll
        for (int o = 32; o > 0; o >>= 1) M = fmaxf(M, __shfl_xor(M, o, 64));
        float thr = M - MARGIN;

        // ---- candidate collection: re-read LDS under divergent guard
        //      (typically 1-2 active lanes; post-patch values, so the true
        //      max element always qualifies) ----
        if (lane == 0) *cnt = 0;
        if (m >= thr) {
#pragma unroll
            for (int c = 0; c < 8; c++) {
                half8v h = *(const half8v*)&g[c * 512 + lane8];
#pragma unroll
                for (int e = 0; e < 8; e++) {
                    float f = fabsf((float)h[e]);
                    if (f >= thr) {
                        int q = atomicAdd(cnt, 1);
                        if (q < MAXC) cand[q] = c * 512 + lane8 + e;
                    }
                }
            }
        }
        __threadfence_block();
        int nc = min(*cnt, MAXC);

        // ---- exact fp64 rescore ----
        int bk; double bv;
        float4 c0, c1;
        if (nc == 1) {
            bk = __builtin_amdgcn_readfirstlane(cand[0]);
            const float* cr = codebook + (size_t)bk * D_SZ + lane8;
            c0 = *(const float4*)cr;
            c1 = *(const float4*)(cr + 4);
            double s = rres[0] * (double)c0.x + rres[1] * (double)c0.y
                     + rres[2] * (double)c0.z + rres[3] * (double)c0.w
                     + rres[4] * (double)c1.x + rres[5] * (double)c1.y
                     + rres[6] * (double)c1.z + rres[7] * (double)c1.w;
#pragma unroll
            for (int o = 32; o > 0; o >>= 1) s += __shfl_xor(s, o, 64);
            bv = s;
        } else {
            bk = -1; bv = 0.0;
            for (int ci = 0; ci < nc; ci++) {
                int k = __builtin_amdgcn_readfirstlane(cand[ci]);
                const float* cr = codebook + (size_t)k * D_SZ + lane8;
                float4 d0 = *(const float4*)cr;
                float4 d1 = *(const float4*)(cr + 4);
                double s = rres[0] * (double)d0.x + rres[1] * (double)d0.y
                         + rres[2] * (double)d0.z + rres[3] * (double)d0.w
                         + rres[4] * (double)d1.x + rres[5] * (double)d1.y
                         + rres[6] * (double)d1.z + rres[7] * (double)d1.w;
#pragma unroll
                for (int o = 32; o > 0; o >>= 1) s += __shfl_xor(s, o, 64);
                if (bk < 0 || fabs(s) > fabs(bv) ||
                    (fabs(s) == fabs(bv) && k < bk)) { bk = k; bv = s; }
            }
            const float* cr = codebook + (size_t)bk * D_SZ + lane8;   // winner row
            c0 = *(const float4*)cr;
            c1 = *(const float4*)(cr + 4);
        }

        // ---- Gram row loads: depend only on bk, issued before fp64 tail ----
        const _Float16* Gp = S + (size_t)(B_SZ + bk) * K_SZ + lane8;
        half8v Gh[8];
#pragma unroll
        for (int c = 0; c < 8; c++) Gh[c] = *(const half8v*)(Gp + c * 512);

        // ---- decision + exact ||r||^2 identity + outputs ----
        const double cn2bk = cn2[bk];
        double sd = ((bv >= 0.0) ? 1.0 : -1.0) * decay;
        rn2 = rn2 - 2.0 * sd * bv + sd * sd * cn2bk;
        if (lane == 0) {
            out_seq[t]  = (float)((bv >= 0.0) ? bk : (-bk - 1));
            out_mask[t] = 1.0f;
        }
        const float sdf = (float)sd;
        h2 sdh2; sdh2[0] = (_Float16)sdf; sdh2[1] = (_Float16)sdf;

        // ---- fused g update (LDS RMW) + next-step lane max ----
        tmax[0] = (_Float16)0; tmax[1] = (_Float16)0;
#pragma unroll
        for (int c = 0; c < 8; c++) {
            half8v gv = *(const half8v*)&g[c * 512 + lane8];
            H2x4 ug = __builtin_bit_cast(H2x4, gv);
            H2x4 uG = __builtin_bit_cast(H2x4, Gh[c]);
            ug.a -= sdh2 * uG.a; ug.b -= sdh2 * uG.b;
            ug.c -= sdh2 * uG.c; ug.d -= sdh2 * uG.d;
            *(half8v*)&g[c * 512 + lane8] = __builtin_bit_cast(half8v, ug);
            tmax = hmax2(tmax, hmax2(hmax2(habs2(ug.a), habs2(ug.b)),
                                     hmax2(habs2(ug.c), habs2(ug.d))));
        }
        m = fmaxf((float)tmax[0], (float)tmax[1]);

        // ---- exact diagonal patch: g[bk] := fp16(bv - sd*||c_bk||^2).
        //      m may be stale-high by <=0.5 on one lane; MARGIN=1.5 covers it,
        //      and the candidate re-read above sees the patched value. ----
        if (lane == 0) g[bk] = (_Float16)(float)(bv - sd * cn2bk);

        // ---- exact fp64 residual update (winner row already in regs) ----
        rres[0] -= sd * (double)c0.x; rres[1] -= sd * (double)c0.y;
        rres[2] -= sd * (double)c0.z; rres[3] -= sd * (double)c0.w;
        rres[4] -= sd * (double)c1.x; rres[5] -= sd * (double)c1.y;
        rres[6] -= sd * (double)c1.z; rres[7] -= sd * (double)c1.w;
    }

    // ---- final residual ----
    {
        float4 r0, r1;
        r0.x = (float)rres[0]; r0.y = (float)rres[1]; r0.z = (float)rres[2]; r0.w = (float)rres[3];
        r1.x = (float)rres[4]; r1.y = (float)rres[5]; r1.z = (float)rres[6]; r1.w = (float)rres[7];
        *(float4*)(out_res + lane8) = r0;
        *(float4*)(out_res + lane8 + 4) = r1;
    }
}

// ---------------------------------------------------------------------------
extern "C" void kernel_launch(void* const* d_in, const int* in_sizes, int n_in,
                              void* d_out, int out_size, void* d_ws, size_t ws_size,
                              hipStream_t stream) {
    const float* targets  = (const float*)d_in[0];
    const float* codebook = (const float*)d_in[1];
    float* out = (float*)d_out;

    __hip_bfloat16* abf = (__hip_bfloat16*)d_ws;                         // 12,582,912 B
    _Float16* S = (_Float16*)((char*)d_ws + (size_t)M_ALL * D_SZ * 2);   // 100,663,296 B
    double* cn2 = (double*)((char*)d_ws + (size_t)M_ALL * D_SZ * 2
                                        + (size_t)M_ALL * K_SZ * 2);     // 32,768 B
    // total ws needed: ~113.3 MB

    int total4 = (M_ALL * D_SZ) / 4;
    cast_bf16_kernel<<<(total4 + 255) / 256, 256, 0, stream>>>(targets, codebook, abf);
    cn2_kernel<<<K_SZ / 4, 256, 0, stream>>>(codebook, cn2);

    dim3 ggrid(K_SZ / BN, M_ALL / BM);
    gemm_bt_kernel<<<ggrid, 256, 0, stream>>>(abf, abf + (size_t)B_SZ * D_SZ, S);

    pursuit_kernel<<<B_SZ / 4, 256, 0, stream>>>(targets, codebook, S, cn2, out);
}

// Round 7
// 335.503 us; speedup vs baseline: 2.1691x; 1.0226x over previous
//
#include <hip/hip_runtime.h>
#include <hip/hip_bf16.h>

// Problem constants
#define B_SZ 8192
#define D_SZ 512
#define K_SZ 4096
#define L_SZ 16
#define M_ALL (B_SZ + K_SZ)   // 12288 rows: targets stacked over codebook

typedef __attribute__((ext_vector_type(8))) short short8v;      // 8 bf16
typedef __attribute__((ext_vector_type(4))) float f32x4;
typedef _Float16 half8v __attribute__((ext_vector_type(8)));    // 8 fp16 = 16B
typedef _Float16 h2 __attribute__((ext_vector_type(2)));        // packed fp16 pair
struct H2x4 { h2 a, b, c, d; };                                 // = one half8v

typedef const __attribute__((address_space(1))) void gvoid;
typedef __attribute__((address_space(3))) void lvoid;

static __device__ __forceinline__ h2 habs2(h2 a) {
    unsigned u = __builtin_bit_cast(unsigned, a) & 0x7FFF7FFFu;
    return __builtin_bit_cast(h2, u);
}
static __device__ __forceinline__ h2 hmax2(h2 a, h2 b) {
#if __has_builtin(__builtin_elementwise_max)
    return __builtin_elementwise_max(a, b);
#else
    h2 r; r[0] = a[0] > b[0] ? a[0] : b[0]; r[1] = a[1] > b[1] ? a[1] : b[1]; return r;
#endif
}

// ---------------------------------------------------------------------------
// Kernel 1: cast targets+codebook (fp32) into one stacked bf16 matrix [12288 x 512]
// ---------------------------------------------------------------------------
__global__ void cast_bf16_kernel(const float* __restrict__ targets,
                                 const float* __restrict__ codebook,
                                 __hip_bfloat16* __restrict__ abf) {
    int idx = blockIdx.x * blockDim.x + threadIdx.x;
    const int total4 = (M_ALL * D_SZ) / 4;
    if (idx >= total4) return;
    int base = idx * 4;
    const float* src = (base < B_SZ * D_SZ) ? (targets + base)
                                            : (codebook + (base - B_SZ * D_SZ));
    float4 v = *(const float4*)src;
    abf[base + 0] = __float2bfloat16(v.x);
    abf[base + 1] = __float2bfloat16(v.y);
    abf[base + 2] = __float2bfloat16(v.z);
    abf[base + 3] = __float2bfloat16(v.w);
}

// ---------------------------------------------------------------------------
// Kernel 1b: exact fp64 codebook row norms^2 (for algebraic ||r||^2 update)
// ---------------------------------------------------------------------------
__global__ void cn2_kernel(const float* __restrict__ codebook,
                           double* __restrict__ cn2) {
    int row  = blockIdx.x * 4 + (threadIdx.x >> 6);
    int lane = threadIdx.x & 63;
    const float* r = codebook + (size_t)row * D_SZ;
    double s = 0.0;
#pragma unroll
    for (int j = 0; j < 8; j++) { double v = (double)r[lane + 64 * j]; s += v * v; }
#pragma unroll
    for (int o = 32; o > 0; o >>= 1) s += __shfl_down(s, o, 64);
    if (lane == 0) cn2[row] = s;
}

// ---------------------------------------------------------------------------
// Kernel 2: S = A * B^T -> fp16 [M x 4096]. 128x128 tile, 4 waves, 16x16x32
// MFMA. m97-style staging: global_load_lds width=16 into UNPADDED [128][32]
// LDS tiles (lane-contiguous: LDS dest = wave base + lane*16 -- required by
// the instruction's wave-uniform-base semantics).
// Score-region output (rows < 8192, read once) stored non-temporal so the
// 32 MiB Gram region stays L3-resident for the pursuit kernel.
// ---------------------------------------------------------------------------
#define BM 128
#define BN 128
#define BK 32   // bf16 elems: 64 B per LDS row, unpadded

__global__ __launch_bounds__(256)
void gemm_bt_kernel(const __hip_bfloat16* __restrict__ A,
                    const __hip_bfloat16* __restrict__ Bm,
                    _Float16* __restrict__ C) {
    __shared__ short As[BM * BK];   // 8 KB
    __shared__ short Bs[BN * BK];   // 8 KB
    const int tid  = threadIdx.x;
    const int bm   = blockIdx.y * BM;
    const int bn   = blockIdx.x * BN;
    const int wave = tid >> 6, lane = tid & 63;
    const int wm = (wave & 1) * 64, wn = (wave >> 1) * 64;
    const int row16 = lane & 15, quad = lane >> 4;
    const int koff = quad * 8;

    f32x4 acc[4][4] = {};

    const short* Ag = (const short*)A;
    const short* Bg = (const short*)Bm;
    const int srow = lane >> 2;          // 0..15 within a 16-row group
    const int scol = (lane & 3) * 8;     // elem offset 0/8/16/24 (16 B chunks)

    for (int k0 = 0; k0 < D_SZ; k0 += BK) {
        __syncthreads();   // protect previous iteration's fragment reads
#pragma unroll
        for (int c = 0; c < 2; c++) {
            int row = (wave * 2 + c) * 16 + srow;
            __builtin_amdgcn_global_load_lds(
                (gvoid*)(Ag + (size_t)(bm + row) * D_SZ + k0 + scol),
                (lvoid*)(As + row * BK + scol), 16, 0, 0);
            __builtin_amdgcn_global_load_lds(
                (gvoid*)(Bg + (size_t)(bn + row) * D_SZ + k0 + scol),
                (lvoid*)(Bs + row * BK + scol), 16, 0, 0);
        }
        __syncthreads();   // drains vmcnt -> LDS tiles complete

        short8v af[4], bf[4];
#pragma unroll
        for (int i = 0; i < 4; i++)
            af[i] = *(const short8v*)(As + (wm + i * 16 + row16) * BK + koff);
#pragma unroll
        for (int j = 0; j < 4; j++)
            bf[j] = *(const short8v*)(Bs + (wn + j * 16 + row16) * BK + koff);
#pragma unroll
        for (int i = 0; i < 4; i++)
#pragma unroll
            for (int j = 0; j < 4; j++)
                acc[i][j] = __builtin_amdgcn_mfma_f32_16x16x32_bf16(af[i], bf[j], acc[i][j], 0, 0, 0);
    }

    // C/D layout: col = lane&15, row = quad*4 + reg  [m89/m91 verified]
    if (bm < B_SZ) {
        // score region: written once, read once by pursuit -> non-temporal
#pragma unroll
        for (int i = 0; i < 4; i++) {
            int grow = bm + wm + i * 16 + quad * 4;
#pragma unroll
            for (int j = 0; j < 4; j++) {
                int gcol = bn + wn + j * 16 + row16;
#pragma unroll
                for (int r = 0; r < 4; r++)
                    __builtin_nontemporal_store((_Float16)acc[i][j][r],
                                                &C[(size_t)(grow + r) * K_SZ + gcol]);
            }
        }
    } else {
        // Gram region: hot random-access data for pursuit -> keep cached
#pragma unroll
        for (int i = 0; i < 4; i++) {
            int grow = bm + wm + i * 16 + quad * 4;
#pragma unroll
            for (int j = 0; j < 4; j++) {
                int gcol = bn + wn + j * 16 + row16;
#pragma unroll
                for (int r = 0; r < 4; r++)
                    C[(size_t)(grow + r) * K_SZ + gcol] = (_Float16)acc[i][j][r];
            }
        }
    }
}

// ---------------------------------------------------------------------------
// Kernel 3: pursuit, wave-per-row, g in LDS as fp16 (8 KB/row, linear,
// conflict-free b128). Persistent regs: rres[8] fp64 + m + rn2 (~24 VGPRs,
// no spill). All streaming read-once traffic (score row, targets, outputs)
// is NON-TEMPORAL so the 32 MiB Gram + 8 MB codebook own the L3.
// ---------------------------------------------------------------------------
#define MAXC 16
#define MARGIN 1.5f

__global__ __launch_bounds__(256, 4)
void pursuit_kernel(const float* __restrict__ targets,
                    const float* __restrict__ codebook,
                    const _Float16* __restrict__ S,   // [12288 x 4096]; rows >=8192 are Gram
                    const double* __restrict__ cn2,   // [4096] exact ||c_k||^2
                    float* __restrict__ out) {
    const int wave = threadIdx.x >> 6;
    const int lane = threadIdx.x & 63;
    const int b = blockIdx.x * 4 + wave;
    const int lane8 = lane * 8;

    __shared__ alignas(16) _Float16 g_s[4][K_SZ];
    __shared__ int s_cnt[4];
    __shared__ int s_cand[4][MAXC];
    _Float16* g = g_s[wave];
    int* cnt  = &s_cnt[wave];
    int* cand = s_cand[wave];

    // ---- init: score row -> LDS (non-temporal), lane max in flight ----
    h2 tmax; tmax[0] = (_Float16)0; tmax[1] = (_Float16)0;
    {
        const _Float16* g0 = S + (size_t)b * K_SZ + lane8;
#pragma unroll
        for (int c = 0; c < 8; c++) {
            half8v h = __builtin_nontemporal_load((const half8v*)(g0 + c * 512));
            *(half8v*)&g[c * 512 + lane8] = h;
            H2x4 u = __builtin_bit_cast(H2x4, h);
            tmax = hmax2(tmax, hmax2(hmax2(habs2(u.a), habs2(u.b)),
                                     hmax2(habs2(u.c), habs2(u.d))));
        }
    }
    float m = fmaxf((float)tmax[0], (float)tmax[1]);

    // ---- lane-private fp64 residual + tn2 (non-temporal target read) ----
    double rres[8];
    double loc = 0.0;
    {
        const float* tg = targets + (size_t)b * D_SZ + lane8;
        f32x4 t0 = __builtin_nontemporal_load((const f32x4*)tg);
        f32x4 t1 = __builtin_nontemporal_load((const f32x4*)(tg + 4));
        rres[0] = t0[0]; rres[1] = t0[1]; rres[2] = t0[2]; rres[3] = t0[3];
        rres[4] = t1[0]; rres[5] = t1[1]; rres[6] = t1[2]; rres[7] = t1[3];
#pragma unroll
        for (int e = 0; e < 8; e++) loc += rres[e] * rres[e];
    }
#pragma unroll
    for (int o = 32; o > 0; o >>= 1) loc += __shfl_xor(loc, o, 64);
    double rn2 = loc;
    const bool tgt_ok = (sqrt(loc) >= 1e-8);

    float* out_seq  = out + (size_t)b * L_SZ;
    float* out_mask = out + (size_t)B_SZ * L_SZ + (size_t)b * L_SZ;
    float* out_res  = out + (size_t)2 * B_SZ * L_SZ + (size_t)b * D_SZ;

    double decay = 1.0;

    for (int t = 0; t < L_SZ; t++) {
        decay *= 0.95;
        bool active = (sqrt(rn2) >= 0.01) && tgt_ok;   // wave-uniform
        if (!active) {                                 // stays inactive forever
            if (lane == 0)
                for (int tt = t; tt < L_SZ; tt++) {
                    __builtin_nontemporal_store(0.0f, &out_seq[tt]);
                    __builtin_nontemporal_store(0.0f, &out_mask[tt]);
                }
            break;
        }

        // ---- wave max + threshold ----
        float M = m;
#pragma unroll
        for (int o = 32; o > 0; o >>= 1) M = fmaxf(M, __shfl_xor(M, o, 64));
        float thr = M - MARGIN;

        // ---- candidate collection: re-read LDS under divergent guard ----
        if (lane == 0) *cnt = 0;
        if (m >= thr) {
#pragma unroll
            for (int c = 0; c < 8; c++) {
                half8v h = *(const half8v*)&g[c * 512 + lane8];
#pragma unroll
                for (int e = 0; e < 8; e++) {
                    float f = fabsf((float)h[e]);
                    if (f >= thr) {
                        int q = atomicAdd(cnt, 1);
                        if (q < MAXC) cand[q] = c * 512 + lane8 + e;
                    }
                }
            }
        }
        __threadfence_block();
        int nc = min(*cnt, MAXC);

        // ---- exact fp64 rescore; Gram loads hoisted off the tail ----
        int bk; double bv;
        float4 c0, c1;
        half8v Gh[8];
        if (nc == 1) {
            bk = __builtin_amdgcn_readfirstlane(cand[0]);
            const float* cr = codebook + (size_t)bk * D_SZ + lane8;
            const _Float16* Gp = S + (size_t)(B_SZ + bk) * K_SZ + lane8;
            c0 = *(const float4*)cr;
            c1 = *(const float4*)(cr + 4);
#pragma unroll
            for (int c = 0; c < 8; c++) Gh[c] = *(const half8v*)(Gp + c * 512);
            double s = rres[0] * (double)c0.x + rres[1] * (double)c0.y
                     + rres[2] * (double)c0.z + rres[3] * (double)c0.w
                     + rres[4] * (double)c1.x + rres[5] * (double)c1.y
                     + rres[6] * (double)c1.z + rres[7] * (double)c1.w;
#pragma unroll
            for (int o = 32; o > 0; o >>= 1) s += __shfl_xor(s, o, 64);
            bv = s;
        } else {
            bk = -1; bv = 0.0;
            for (int ci = 0; ci < nc; ci++) {
                int k = __builtin_amdgcn_readfirstlane(cand[ci]);
                const float* cr = codebook + (size_t)k * D_SZ + lane8;
                float4 d0 = *(const float4*)cr;
                float4 d1 = *(const float4*)(cr + 4);
                double s = rres[0] * (double)d0.x + rres[1] * (double)d0.y
                         + rres[2] * (double)d0.z + rres[3] * (double)d0.w
                         + rres[4] * (double)d1.x + rres[5] * (double)d1.y
                         + rres[6] * (double)d1.z + rres[7] * (double)d1.w;
#pragma unroll
                for (int o = 32; o > 0; o >>= 1) s += __shfl_xor(s, o, 64);
                if (bk < 0 || fabs(s) > fabs(bv) ||
                    (fabs(s) == fabs(bv) && k < bk)) { bk = k; bv = s; }
            }
            const float* cr = codebook + (size_t)bk * D_SZ + lane8;   // winner row
            const _Float16* Gp = S + (size_t)(B_SZ + bk) * K_SZ + lane8;
            c0 = *(const float4*)cr;
            c1 = *(const float4*)(cr + 4);
#pragma unroll
            for (int c = 0; c < 8; c++) Gh[c] = *(const half8v*)(Gp + c * 512);
        }

        // ---- decision + exact ||r||^2 identity + outputs ----
        const double cn2bk = cn2[bk];
        double sd = ((bv >= 0.0) ? 1.0 : -1.0) * decay;
        rn2 = rn2 - 2.0 * sd * bv + sd * sd * cn2bk;
        if (lane == 0) {
            __builtin_nontemporal_store((float)((bv >= 0.0) ? bk : (-bk - 1)), &out_seq[t]);
            __builtin_nontemporal_store(1.0f, &out_mask[t]);
        }
        const float sdf = (float)sd;
        h2 sdh2; sdh2[0] = (_Float16)sdf; sdh2[1] = (_Float16)sdf;

        // ---- fused g update (LDS RMW) + next-step lane max ----
        tmax[0] = (_Float16)0; tmax[1] = (_Float16)0;
#pragma unroll
        for (int c = 0; c < 8; c++) {
            half8v gv = *(const half8v*)&g[c * 512 + lane8];
            H2x4 ug = __builtin_bit_cast(H2x4, gv);
            H2x4 uG = __builtin_bit_cast(H2x4, Gh[c]);
            ug.a -= sdh2 * uG.a; ug.b -= sdh2 * uG.b;
            ug.c -= sdh2 * uG.c; ug.d -= sdh2 * uG.d;
            *(half8v*)&g[c * 512 + lane8] = __builtin_bit_cast(half8v, ug);
            tmax = hmax2(tmax, hmax2(hmax2(habs2(ug.a), habs2(ug.b)),
                                     hmax2(habs2(ug.c), habs2(ug.d))));
        }
        m = fmaxf((float)tmax[0], (float)tmax[1]);

        // ---- exact diagonal patch: g[bk] := fp16(bv - sd*||c_bk||^2).
        //      m may be stale-high by <=0.5 on one lane; MARGIN=1.5 covers it,
        //      and the candidate re-read above sees the patched value. ----
        if (lane == 0) g[bk] = (_Float16)(float)(bv - sd * cn2bk);

        // ---- exact fp64 residual update (winner row already in regs) ----
        rres[0] -= sd * (double)c0.x; rres[1] -= sd * (double)c0.y;
        rres[2] -= sd * (double)c0.z; rres[3] -= sd * (double)c0.w;
        rres[4] -= sd * (double)c1.x; rres[5] -= sd * (double)c1.y;
        rres[6] -= sd * (double)c1.z; rres[7] -= sd * (double)c1.w;
    }

    // ---- final residual (non-temporal) ----
    {
        f32x4 r0, r1;
        r0[0] = (float)rres[0]; r0[1] = (float)rres[1]; r0[2] = (float)rres[2]; r0[3] = (float)rres[3];
        r1[0] = (float)rres[4]; r1[1] = (float)rres[5]; r1[2] = (float)rres[6]; r1[3] = (float)rres[7];
        __builtin_nontemporal_store(r0, (f32x4*)(out_res + lane8));
        __builtin_nontemporal_store(r1, (f32x4*)(out_res + lane8 + 4));
    }
}

// ---------------------------------------------------------------------------
extern "C" void kernel_launch(void* const* d_in, const int* in_sizes, int n_in,
                              void* d_out, int out_size, void* d_ws, size_t ws_size,
                              hipStream_t stream) {
    const float* targets  = (const float*)d_in[0];
    const float* codebook = (const float*)d_in[1];
    float* out = (float*)d_out;

    __hip_bfloat16* abf = (__hip_bfloat16*)d_ws;                         // 12,582,912 B
    _Float16* S = (_Float16*)((char*)d_ws + (size_t)M_ALL * D_SZ * 2);   // 100,663,296 B
    double* cn2 = (double*)((char*)d_ws + (size_t)M_ALL * D_SZ * 2
                                        + (size_t)M_ALL * K_SZ * 2);     // 32,768 B
    // total ws needed: ~113.3 MB

    int total4 = (M_ALL * D_SZ) / 4;
    cast_bf16_kernel<<<(total4 + 255) / 256, 256, 0, stream>>>(targets, codebook, abf);
    cn2_kernel<<<K_SZ / 4, 256, 0, stream>>>(codebook, cn2);

    dim3 ggrid(K_SZ / BN, M_ALL / BM);
    gemm_bt_kernel<<<ggrid, 256, 0, stream>>>(abf, abf + (size_t)B_SZ * D_SZ, S);

    pursuit_kernel<<<B_SZ / 4, 256, 0, stream>>>(targets, codebook, S, cn2, out);
}